// Round 3
// baseline (403.652 us; speedup 1.0000x reference)
//
#include <hip/hip_runtime.h>
#include <hip/hip_bf16.h>

#define N_NODES 100000
#define N_EDGES 600000
#define D_IN 128
#define D_OUT 512
#define CAP 40        // bucket capacity per node (Poisson(6): P(deg>=40) ~ 1e-20)
#define OVF_CAP 1024

typedef __bf16 bf16x8 __attribute__((ext_vector_type(8)));
typedef __bf16 bf16x2 __attribute__((ext_vector_type(2)));
typedef float f32x4 __attribute__((ext_vector_type(4)));

// ---- workspace layout (bytes) ----
#define OFF_CNT   25600000
#define OFF_OVFC  26000000
#define OFF_OVF   26000016
#define OFF_BUCK  26008208

// ---------------- kernel 1: build per-node buckets --------------------------
__global__ void k_bucket(const int* __restrict__ ei, int* __restrict__ cnt,
                         int* __restrict__ bucket, int* __restrict__ ovf_cnt,
                         int2* __restrict__ ovf) {
    int e = blockIdx.x * blockDim.x + threadIdx.x;
    if (e >= N_EDGES) return;
    int r = ei[e];            // destination
    int c = ei[N_EDGES + e];  // source
    int slot = atomicAdd(&cnt[r], 1);
    if (slot < CAP) {
        bucket[(size_t)r * CAP + slot] = c;
    } else {
        int oi = atomicAdd(ovf_cnt, 1);
        if (oi < OVF_CAP) ovf[oi] = make_int2(r, c);
    }
}

// ---------------- kernel 2: h[r] = bf16( x[r] + sum_{c in bucket[r]} x[c] ) -
__global__ void k_agg(const float* __restrict__ x, const int* __restrict__ cnt,
                      const int* __restrict__ bucket, const int* __restrict__ ovf_cnt,
                      const int2* __restrict__ ovf, __bf16* __restrict__ h) {
    int gw = (blockIdx.x * blockDim.x + threadIdx.x) >> 6;  // wave id = node
    if (gw >= N_NODES) return;
    int lane = threadIdx.x & 63;
    const float2* xr = (const float2*)x;

    float2 acc = xr[(size_t)gw * 64 + lane];  // residual x[gw]
    float ax2 = 0.f, ay2 = 0.f;

    int deg = __builtin_amdgcn_readfirstlane(cnt[gw]);
    int dmin = deg < CAP ? deg : CAP;
    const int* bk = bucket + (size_t)gw * CAP;

    int d = 0;
    for (; d + 1 < dmin; d += 2) {
        int c0 = __builtin_amdgcn_readfirstlane(bk[d]);
        int c1 = __builtin_amdgcn_readfirstlane(bk[d + 1]);
        float2 v0 = xr[(size_t)c0 * 64 + lane];
        float2 v1 = xr[(size_t)c1 * 64 + lane];
        acc.x += v0.x; acc.y += v0.y;
        ax2 += v1.x;   ay2 += v1.y;
    }
    if (d < dmin) {
        int c0 = __builtin_amdgcn_readfirstlane(bk[d]);
        float2 v0 = xr[(size_t)c0 * 64 + lane];
        acc.x += v0.x; acc.y += v0.y;
    }
    acc.x += ax2; acc.y += ay2;

    if (deg > CAP) {  // statistically never; correctness fallback
        int n = *ovf_cnt;
        if (n > OVF_CAP) n = OVF_CAP;
        for (int i = 0; i < n; ++i) {
            int2 e = ovf[i];
            if (e.x == gw) {
                float2 v = xr[(size_t)e.y * 64 + lane];
                acc.x += v.x; acc.y += v.y;
            }
        }
    }

    bf16x2 o = { (__bf16)acc.x, (__bf16)acc.y };
    ((bf16x2*)h)[(size_t)gw * 64 + lane] = o;
}

// ---------------- kernel 3: out = h @ W^T + b (register-resident B) ---------
// M=100000 (6250 strips of 16 rows), N=512 split into 4 column-quarters of 128.
// Each wave holds its W-quarter entirely in VGPRs (8 nt x 4 ks x 4 VGPR = 128),
// loops over m-strips: 4 a-frag gathers + 32 MFMA + 32 stores. No LDS, no
// barriers. Grid dim3(4,128) = 512 blocks = exactly 2/CU, 8 waves/CU.
#define N_STRIPS 6250          // 100000 / 16, exact
#define WAVE_SLOTS 512         // 128 blocks * 4 waves per n-quarter
#define GEMM_ITERS 13          // ceil(6250 / 512)

__device__ inline bf16x8 cvt8(float4 v0, float4 v1) {
    bf16x8 u = { (__bf16)v0.x, (__bf16)v0.y, (__bf16)v0.z, (__bf16)v0.w,
                 (__bf16)v1.x, (__bf16)v1.y, (__bf16)v1.z, (__bf16)v1.w };
    return u;
}

__launch_bounds__(256, 2)
__global__ void k_gemm(const __bf16* __restrict__ h, const float* __restrict__ W,
                       const float* __restrict__ bias, float* __restrict__ out) {
    int tid = threadIdx.x;
    int lane = tid & 63;
    int wave = tid >> 6;
    int nq = blockIdx.x;          // column quarter: cols [nq*128, nq*128+128)
    int q = lane >> 4;            // k-quad
    int n16 = lane & 15;

    // ---- B fragments in registers: W[nq*128 + nt*16 + n16][ks*32 + q*8 ..+8)
    bf16x8 bfrag[8][4];
    {
        const float* wb = W + (size_t)(nq * 128 + n16) * D_IN + q * 8;
        #pragma unroll
        for (int nt = 0; nt < 8; ++nt)
            #pragma unroll
            for (int ks = 0; ks < 4; ++ks) {
                const float* src = wb + (size_t)nt * 16 * D_IN + ks * 32;
                float4 v0 = *(const float4*)(src);
                float4 v1 = *(const float4*)(src + 4);
                bfrag[nt][ks] = cvt8(v0, v1);
            }
    }
    float biasr[8];
    #pragma unroll
    for (int nt = 0; nt < 8; ++nt)
        biasr[nt] = bias[nq * 128 + nt * 16 + n16];

    int g = blockIdx.y * 4 + wave;      // strip id, advances by 512

    // prologue: load a-frags for first strip
    bf16x8 af[4];
    if (g < N_STRIPS) {
        const __bf16* ab = h + (size_t)(g * 16 + n16) * D_IN + q * 8;
        #pragma unroll
        for (int ks = 0; ks < 4; ++ks) af[ks] = *(const bf16x8*)(ab + ks * 32);
    }

    for (int it = 0; it < GEMM_ITERS; ++it) {
        int gn = g + WAVE_SLOTS;
        // prefetch next strip's a-frags (overlaps with MFMA + stores below)
        bf16x8 afn[4];
        if (it + 1 < GEMM_ITERS && gn < N_STRIPS) {
            const __bf16* ab = h + (size_t)(gn * 16 + n16) * D_IN + q * 8;
            #pragma unroll
            for (int ks = 0; ks < 4; ++ks) afn[ks] = *(const bf16x8*)(ab + ks * 32);
        }
        if (g < N_STRIPS) {
            f32x4 acc[8] = {};
            #pragma unroll
            for (int ks = 0; ks < 4; ++ks)
                #pragma unroll
                for (int nt = 0; nt < 8; ++nt)
                    acc[nt] = __builtin_amdgcn_mfma_f32_16x16x32_bf16(
                        af[ks], bfrag[nt][ks], acc[nt], 0, 0, 0);
            // C layout: col = n16, row = q*4 + reg
            float* ob = out + (size_t)(g * 16 + q * 4) * D_OUT + nq * 128 + n16;
            #pragma unroll
            for (int nt = 0; nt < 8; ++nt) {
                #pragma unroll
                for (int rg = 0; rg < 4; ++rg)
                    ob[(size_t)rg * D_OUT + nt * 16] = acc[nt][rg] + biasr[nt];
            }
        }
        g = gn;
        #pragma unroll
        for (int ks = 0; ks < 4; ++ks) af[ks] = afn[ks];
    }
}

extern "C" void kernel_launch(void* const* d_in, const int* in_sizes, int n_in,
                              void* d_out, int out_size, void* d_ws, size_t ws_size,
                              hipStream_t stream) {
    const float* x  = (const float*)d_in[0];
    const int*   ei = (const int*)d_in[1];
    const float* W  = (const float*)d_in[2];
    const float* b  = (const float*)d_in[3];
    float* out = (float*)d_out;

    char* ws = (char*)d_ws;
    __bf16* h    = (__bf16*)ws;
    int* cnt     = (int*)(ws + OFF_CNT);
    int* ovf_cnt = (int*)(ws + OFF_OVFC);
    int2* ovf    = (int2*)(ws + OFF_OVF);
    int* bucket  = (int*)(ws + OFF_BUCK);

    hipMemsetAsync(cnt, 0, (OFF_OVFC - OFF_CNT) + 16, stream);

    k_bucket<<<(N_EDGES + 255) / 256, 256, 0, stream>>>(ei, cnt, bucket, ovf_cnt, ovf);
    k_agg<<<(N_NODES * 64 + 255) / 256, 256, 0, stream>>>(x, cnt, bucket, ovf_cnt, ovf, h);
    k_gemm<<<dim3(4, 128), 256, 0, stream>>>(h, W, b, out);
}